// Round 3
// baseline (315.648 us; speedup 1.0000x reference)
//
#include <hip/hip_runtime.h>
#include <math.h>

#define B_ 8
#define L_ 64
#define D_ 1024
#define N_ 128
#define R_ 64

__device__ __forceinline__ float silu_f(float x) { return x / (1.f + __expf(-x)); }
__device__ __forceinline__ float softplus_f(float x) {
    return fmaxf(x, 0.f) + log1pf(__expf(-fabsf(x)));
}

// C[m,n] = act( sum_k A[m,k]*W[n,k] + bias[n] )
// ACT: 0 = none, 1 = store raw to C and silu to C2, 2 = softplus
// Tile: 32 (M) x 64 (N), 128 threads, 4x4 outputs/thread.
template <int ACT>
__launch_bounds__(128)
__global__ void gemm_nt(const float* __restrict__ A, int lda,
                        const float* __restrict__ W, int ldw,
                        const float* __restrict__ bias,
                        float* __restrict__ C, float* __restrict__ C2,
                        int N, int K)
{
    __shared__ float As[32][33];
    __shared__ float Wsh[64][33];
    const int tid = threadIdx.x;
    const int tx = tid & 15;   // n-dir
    const int ty = tid >> 4;   // m-dir
    const int m0 = blockIdx.y * 32;
    const int n0 = blockIdx.x * 64;

    float acc[4][4] = {};

    for (int k0 = 0; k0 < K; k0 += 32) {
        // A tile: 32x32 = 256 float4 loads (2/thread)
        #pragma unroll
        for (int i = 0; i < 2; ++i) {
            int c = tid + 128 * i;
            int r = c >> 3, c4 = c & 7;
            float4 v = *reinterpret_cast<const float4*>(
                A + (size_t)(m0 + r) * lda + k0 + c4 * 4);
            As[r][c4 * 4 + 0] = v.x; As[r][c4 * 4 + 1] = v.y;
            As[r][c4 * 4 + 2] = v.z; As[r][c4 * 4 + 3] = v.w;
        }
        // W tile: 64x32 = 512 float4 loads (4/thread)
        #pragma unroll
        for (int i = 0; i < 4; ++i) {
            int c = tid + 128 * i;
            int r = c >> 3, c4 = c & 7;
            float4 v = *reinterpret_cast<const float4*>(
                W + (size_t)(n0 + r) * ldw + k0 + c4 * 4);
            Wsh[r][c4 * 4 + 0] = v.x; Wsh[r][c4 * 4 + 1] = v.y;
            Wsh[r][c4 * 4 + 2] = v.z; Wsh[r][c4 * 4 + 3] = v.w;
        }
        __syncthreads();
        #pragma unroll
        for (int kk = 0; kk < 32; ++kk) {
            float a[4], w[4];
            #pragma unroll
            for (int i = 0; i < 4; ++i) a[i] = As[ty * 4 + i][kk];
            #pragma unroll
            for (int j = 0; j < 4; ++j) w[j] = Wsh[tx * 4 + j][kk];
            #pragma unroll
            for (int i = 0; i < 4; ++i)
                #pragma unroll
                for (int j = 0; j < 4; ++j)
                    acc[i][j] = fmaf(a[i], w[j], acc[i][j]);
        }
        __syncthreads();
    }

    #pragma unroll
    for (int j = 0; j < 4; ++j) {
        int n = n0 + tx * 4 + j;
        float bj = bias ? bias[n] : 0.f;
        #pragma unroll
        for (int i = 0; i < 4; ++i) {
            int m = m0 + ty * 4 + i;
            float c = acc[i][j] + bj;
            size_t idx = (size_t)m * N + n;
            if (ACT == 2) c = softplus_f(c);
            C[idx] = c;
            if (ACT == 1) C2[idx] = silu_f(c);
        }
    }
}

// x_one[b,lo,d] = silu( conv_b[lo] + sum_{li,t} xp[b,li,d+t-1] * conv_w[lo,li,t] )
__launch_bounds__(256)
__global__ void conv_silu(const float* __restrict__ xp,
                          const float* __restrict__ conv_w,
                          const float* __restrict__ conv_b,
                          float* __restrict__ x_one)
{
    __shared__ float ws[192][65];  // [(li*3+t)][lo], padded to kill bank conflicts
    __shared__ float xs[64][34];   // [li][dd], dd -> global d = d0-1+dd
    const int tid = threadIdx.x;
    const int b = blockIdx.y;
    const int d0 = blockIdx.x * 32;

    for (int idx = tid; idx < 64 * 64 * 3; idx += 256) {
        int lo = idx / 192, r = idx % 192;
        ws[r][lo] = conv_w[idx];
    }
    for (int idx = tid; idx < 64 * 34; idx += 256) {
        int li = idx / 34, dd = idx % 34;
        int g = d0 - 1 + dd;
        xs[li][dd] = (g >= 0 && g < D_) ? xp[((size_t)b * L_ + li) * D_ + g] : 0.f;
    }
    __syncthreads();

    const int lo = tid >> 2;           // 0..63
    const int dbase = (tid & 3) * 8;   // 0,8,16,24
    float acc[8] = {};
    #pragma unroll 4
    for (int li = 0; li < 64; ++li) {
        float w0 = ws[li * 3 + 0][lo];
        float w1 = ws[li * 3 + 1][lo];
        float w2 = ws[li * 3 + 2][lo];
        float xv[10];
        #pragma unroll
        for (int j = 0; j < 10; ++j) xv[j] = xs[li][dbase + j];
        #pragma unroll
        for (int i = 0; i < 8; ++i)
            acc[i] = fmaf(w0, xv[i], fmaf(w1, xv[i + 1], fmaf(w2, xv[i + 2], acc[i])));
    }
    float bb = conv_b[lo];
    #pragma unroll
    for (int i = 0; i < 8; ++i) {
        float c = acc[i] + bb;
        x_one[((size_t)b * L_ + lo) * D_ + d0 + dbase + i] = silu_f(c);
    }
}

// One wave per (b,d). Lane ln owns states n=ln and n=ln+64.
// h_l = exp(delta*A)*h_{l-1} + delta*Bm*x ; y_l = sum_n h_l*Cm ; fused epilogue.
__launch_bounds__(256)
__global__ void ssm_scan(const float* __restrict__ dbc,
                         const float* __restrict__ delta,
                         const float* __restrict__ x_one,
                         const float* __restrict__ x_two,
                         const float* __restrict__ skip,
                         const float* __restrict__ A_log,
                         const float* __restrict__ Dp,
                         float* __restrict__ out_mid)
{
    __shared__ float dl_s[4][64], xo_s[4][64], pt[4][64];
    const int tid = threadIdx.x;
    const int w = tid >> 6, ln = tid & 63;
    const int b = blockIdx.y;
    const int d = blockIdx.x * 4 + w;

    dl_s[w][ln] = delta[((size_t)b * L_ + ln) * D_ + d];
    xo_s[w][ln] = x_one[((size_t)b * L_ + ln) * D_ + d];
    const float a0 = -__expf(A_log[(size_t)d * N_ + ln]);
    const float a1 = -__expf(A_log[(size_t)d * N_ + 64 + ln]);
    __syncthreads();

    float h0 = 0.f, h1 = 0.f;
    const float* base = dbc + (size_t)b * L_ * 320;
    for (int l = 0; l < 64; ++l) {
        const float* row = base + l * 320;
        float Bc0 = row[64 + ln],  Bc1 = row[128 + ln];
        float Cc0 = row[192 + ln], Cc1 = row[256 + ln];
        float dl = dl_s[w][l], xo = xo_s[w][l];
        float dx = dl * xo;
        h0 = __expf(dl * a0) * h0 + dx * Bc0;
        h1 = __expf(dl * a1) * h1 + dx * Bc1;
        float p = h0 * Cc0 + h1 * Cc1;
        #pragma unroll
        for (int off = 32; off > 0; off >>= 1) p += __shfl_xor(p, off, 64);
        if (ln == 0) pt[w][l] = p;
    }
    __syncthreads();

    {
        int l = ln;
        size_t idx = ((size_t)b * L_ + l) * D_ + d;
        float y = pt[w][l] + Dp[d] * xo_s[w][l];
        out_mid[idx] = y * x_two[idx] + skip[idx];
    }
}

extern "C" void kernel_launch(void* const* d_in, const int* in_sizes, int n_in,
                              void* d_out, int out_size, void* d_ws, size_t ws_size,
                              hipStream_t stream)
{
    const float* x      = (const float*)d_in[0];
    const float* proj_w = (const float*)d_in[1];
    const float* proj_b = (const float*)d_in[2];
    const float* conv_w = (const float*)d_in[3];
    const float* conv_b = (const float*)d_in[4];
    const float* dbc_w  = (const float*)d_in[5];
    const float* dt_w   = (const float*)d_in[6];
    const float* dt_b   = (const float*)d_in[7];
    const float* A_log  = (const float*)d_in[8];
    const float* Dp     = (const float*)d_in[9];
    float* out = (float*)d_out;

    float* ws      = (float*)d_ws;
    float* xp      = ws;                  // 524288
    float* x_two   = xp + 524288;         // 524288
    float* x_one   = x_two + 524288;      // 524288
    float* dbc     = x_one + 524288;      // 163840
    float* delta   = dbc + 163840;        // 524288
    float* out_mid = delta + 524288;      // 524288

    const int M = B_ * L_;  // 512

    // 1) xp = x @ proj_w.T + proj_b ; x_two = silu(xp)
    gemm_nt<1><<<dim3(D_ / 64, M / 32), 128, 0, stream>>>(
        x, D_, proj_w, D_, proj_b, xp, x_two, D_, D_);
    // 2) x_one = silu(conv(xp))
    conv_silu<<<dim3(D_ / 32, B_), 256, 0, stream>>>(xp, conv_w, conv_b, x_one);
    // 3) dbc = x_one @ dbc_w.T   (N = 320)
    gemm_nt<0><<<dim3(320 / 64, M / 32), 128, 0, stream>>>(
        x_one, D_, dbc_w, D_, nullptr, dbc, nullptr, 320, D_);
    // 4) delta = softplus(dbc[:, :64] @ dt_w.T + dt_b)
    gemm_nt<2><<<dim3(D_ / 64, M / 32), 128, 0, stream>>>(
        dbc, 320, dt_w, R_, dt_b, delta, nullptr, D_, R_);
    // 5) fused SSM scan + gating + skip
    ssm_scan<<<dim3(D_ / 4, B_), 256, 0, stream>>>(
        dbc, delta, x_one, x_two, x, A_log, Dp, out_mid);
    // 6) out = out_mid @ proj_w.T + proj_b
    gemm_nt<0><<<dim3(D_ / 64, M / 32), 128, 0, stream>>>(
        out_mid, D_, proj_w, D_, proj_b, out, nullptr, D_, D_);
}

// Round 4
// 204.392 us; speedup vs baseline: 1.5443x; 1.5443x over previous
//
#include <hip/hip_runtime.h>
#include <math.h>

#define B_ 8
#define L_ 64
#define D_ 1024
#define N_ 128
#define R_ 64

typedef unsigned short u16;
typedef __bf16 bf16x8 __attribute__((ext_vector_type(8)));
typedef u16 u16x8 __attribute__((ext_vector_type(8)));
typedef float floatx4 __attribute__((ext_vector_type(4)));

__device__ __forceinline__ float silu_f(float x) { return x / (1.f + __expf(-x)); }
__device__ __forceinline__ float softplus_f(float x) {
    return fmaxf(x, 0.f) + log1pf(__expf(-fabsf(x)));
}

// Convert weights to bf16 once per call. Chunks of 8 floats.
// pw: 1024*1024 (131072 chunks), dbcw: 320*1024 (40960), dtw: 1024*64 (8192)
__launch_bounds__(256)
__global__ void prep_bf16(const float* __restrict__ pw,
                          const float* __restrict__ dbcw,
                          const float* __restrict__ dtw,
                          __bf16* __restrict__ pw_b,
                          __bf16* __restrict__ dbcw_b,
                          __bf16* __restrict__ dtw_b)
{
    int gid = blockIdx.x * blockDim.x + threadIdx.x;
    const float* src; __bf16* dst; int off;
    if (gid < 131072)       { src = pw;   dst = pw_b;   off = gid * 8; }
    else if (gid < 172032)  { src = dbcw; dst = dbcw_b; off = (gid - 131072) * 8; }
    else if (gid < 180224)  { src = dtw;  dst = dtw_b;  off = (gid - 172032) * 8; }
    else return;
    float4 f0 = *reinterpret_cast<const float4*>(src + off);
    float4 f1 = *reinterpret_cast<const float4*>(src + off + 4);
    bf16x8 v;
    v[0] = (__bf16)f0.x; v[1] = (__bf16)f0.y; v[2] = (__bf16)f0.z; v[3] = (__bf16)f0.w;
    v[4] = (__bf16)f1.x; v[5] = (__bf16)f1.y; v[6] = (__bf16)f1.z; v[7] = (__bf16)f1.w;
    *reinterpret_cast<bf16x8*>(dst + off) = v;
}

// C[m,n] = act( sum_k A[m,k]*W[n,k] + bias[n] )   (NT: W row-major [n][k])
// BK=64. WM*WN waves; wave tile (BM/WM == 16) x (BN/WN); NREP = BN/WN/16.
// LDS tiles [row][64] bf16 with 16B-chunk XOR swizzle: chunk ^= (row&7).
// ACT: 0 none, 1 raw->C + silu->C2, 2 softplus. AF32: A operand is f32.
// OUTF32: C is float (else bf16).
template <int BM, int BN, int WM, int WN, int ACT, int AF32, int OUTF32>
__launch_bounds__(WM * WN * 64)
__global__ void gemm_mfma(const void* __restrict__ Ap, int lda,
                          const __bf16* __restrict__ W, int ldw,
                          const float* __restrict__ bias,
                          void* __restrict__ Cp, __bf16* __restrict__ C2,
                          int ldc, int K)
{
    constexpr int NTHR = WM * WN * 64;
    constexpr int NREP = BN / WN / 16;
    __shared__ u16 As[BM * 64];
    __shared__ u16 Bs[BN * 64];
    const int tid = threadIdx.x;
    const int l   = tid & 63;
    const int w   = tid >> 6;
    const int wm  = w / WN, wn = w % WN;
    const int m0  = blockIdx.y * BM;
    const int n0  = blockIdx.x * BN;

    floatx4 acc[NREP];
    #pragma unroll
    for (int i = 0; i < NREP; ++i) acc[i] = (floatx4)0.0f;

    for (int k0 = 0; k0 < K; k0 += 64) {
        #pragma unroll
        for (int idx = tid; idx < BM * 8; idx += NTHR) {
            int r = idx >> 3, c = idx & 7;
            u16* dst = &As[r * 64 + ((c ^ (r & 7)) * 8)];
            if (AF32) {
                const float* src = (const float*)Ap + (size_t)(m0 + r) * lda + k0 + c * 8;
                float4 f0 = *reinterpret_cast<const float4*>(src);
                float4 f1 = *reinterpret_cast<const float4*>(src + 4);
                bf16x8 v;
                v[0] = (__bf16)f0.x; v[1] = (__bf16)f0.y; v[2] = (__bf16)f0.z; v[3] = (__bf16)f0.w;
                v[4] = (__bf16)f1.x; v[5] = (__bf16)f1.y; v[6] = (__bf16)f1.z; v[7] = (__bf16)f1.w;
                *reinterpret_cast<bf16x8*>(dst) = v;
            } else {
                const u16* src = (const u16*)Ap + (size_t)(m0 + r) * lda + k0 + c * 8;
                *reinterpret_cast<u16x8*>(dst) = *reinterpret_cast<const u16x8*>(src);
            }
        }
        #pragma unroll
        for (int idx = tid; idx < BN * 8; idx += NTHR) {
            int r = idx >> 3, c = idx & 7;
            const u16* src = (const u16*)W + (size_t)(n0 + r) * ldw + k0 + c * 8;
            *reinterpret_cast<u16x8*>(&Bs[r * 64 + ((c ^ (r & 7)) * 8)]) =
                *reinterpret_cast<const u16x8*>(src);
        }
        __syncthreads();
        #pragma unroll
        for (int s = 0; s < 2; ++s) {
            const int ra = wm * 16 + (l & 15);
            const int ca = (s * 4 + (l >> 4)) ^ (ra & 7);
            bf16x8 a = *reinterpret_cast<const bf16x8*>(&As[ra * 64 + ca * 8]);
            #pragma unroll
            for (int nf = 0; nf < NREP; ++nf) {
                const int rb = wn * (BN / WN) + nf * 16 + (l & 15);
                const int cb = (s * 4 + (l >> 4)) ^ (rb & 7);
                bf16x8 b = *reinterpret_cast<const bf16x8*>(&Bs[rb * 64 + cb * 8]);
                acc[nf] = __builtin_amdgcn_mfma_f32_16x16x32_bf16(a, b, acc[nf], 0, 0, 0);
            }
        }
        __syncthreads();
    }

    #pragma unroll
    for (int nf = 0; nf < NREP; ++nf) {
        const int n = n0 + wn * (BN / WN) + nf * 16 + (l & 15);
        const float bj = bias ? bias[n] : 0.f;
        #pragma unroll
        for (int r = 0; r < 4; ++r) {
            const int m = m0 + wm * 16 + (l >> 4) * 4 + r;
            float c = acc[nf][r] + bj;
            if (ACT == 2) c = softplus_f(c);
            const size_t idx = (size_t)m * ldc + n;
            if (OUTF32) ((float*)Cp)[idx] = c;
            else        ((__bf16*)Cp)[idx] = (__bf16)c;
            if (ACT == 1) C2[idx] = (__bf16)silu_f(c);
        }
    }
}

// x_one[b,lo,d] = silu( conv_b[lo] + sum_{li,t} xp[b,li,d+t-1] * conv_w[lo,li,t] )
__launch_bounds__(256)
__global__ void conv_silu(const __bf16* __restrict__ xp,
                          const float* __restrict__ conv_w,
                          const float* __restrict__ conv_b,
                          __bf16* __restrict__ x_one)
{
    __shared__ float ws[192][65];
    __shared__ float xs[64][34];
    const int tid = threadIdx.x;
    const int b = blockIdx.y;
    const int d0 = blockIdx.x * 32;

    for (int idx = tid; idx < 64 * 64 * 3; idx += 256) {
        int lo = idx / 192, r = idx % 192;
        ws[r][lo] = conv_w[idx];
    }
    for (int idx = tid; idx < 64 * 34; idx += 256) {
        int li = idx / 34, dd = idx % 34;
        int g = d0 - 1 + dd;
        xs[li][dd] = (g >= 0 && g < D_) ? (float)xp[((size_t)b * L_ + li) * D_ + g] : 0.f;
    }
    __syncthreads();

    const int lo = tid >> 2;
    const int dbase = (tid & 3) * 8;
    float acc[8] = {};
    #pragma unroll 4
    for (int li = 0; li < 64; ++li) {
        float w0 = ws[li * 3 + 0][lo];
        float w1 = ws[li * 3 + 1][lo];
        float w2 = ws[li * 3 + 2][lo];
        float xv[10];
        #pragma unroll
        for (int j = 0; j < 10; ++j) xv[j] = xs[li][dbase + j];
        #pragma unroll
        for (int i = 0; i < 8; ++i)
            acc[i] = fmaf(w0, xv[i], fmaf(w1, xv[i + 1], fmaf(w2, xv[i + 2], acc[i])));
    }
    float bb = conv_b[lo];
    bf16x8 v;
    #pragma unroll
    for (int i = 0; i < 8; ++i) v[i] = (__bf16)silu_f(acc[i] + bb);
    *reinterpret_cast<bf16x8*>(&x_one[((size_t)b * L_ + lo) * D_ + d0 + dbase]) = v;
}

// One wave per (b,d). Lane ln owns states n=ln and n=ln+64. f32 state, bf16 I/O.
__launch_bounds__(256)
__global__ void ssm_scan(const __bf16* __restrict__ dbc,
                         const __bf16* __restrict__ dl_in,
                         const __bf16* __restrict__ xo_in,
                         const __bf16* __restrict__ xt_in,
                         const float* __restrict__ skip,
                         const float* __restrict__ A_log,
                         const float* __restrict__ Dp,
                         __bf16* __restrict__ out_mid)
{
    __shared__ float dl_s[4][64], xo_s[4][64], pt[4][64];
    const int tid = threadIdx.x;
    const int w = tid >> 6, ln = tid & 63;
    const int b = blockIdx.y;
    const int d = blockIdx.x * 4 + w;

    dl_s[w][ln] = (float)dl_in[((size_t)b * L_ + ln) * D_ + d];
    xo_s[w][ln] = (float)xo_in[((size_t)b * L_ + ln) * D_ + d];
    const float a0 = -__expf(A_log[(size_t)d * N_ + ln]);
    const float a1 = -__expf(A_log[(size_t)d * N_ + 64 + ln]);
    __syncthreads();

    float h0 = 0.f, h1 = 0.f;
    const __bf16* base = dbc + (size_t)b * L_ * 320;
    for (int l = 0; l < 64; ++l) {
        const __bf16* row = base + l * 320;
        float Bc0 = (float)row[64 + ln],  Bc1 = (float)row[128 + ln];
        float Cc0 = (float)row[192 + ln], Cc1 = (float)row[256 + ln];
        float dl = dl_s[w][l], xo = xo_s[w][l];
        float dx = dl * xo;
        h0 = __expf(dl * a0) * h0 + dx * Bc0;
        h1 = __expf(dl * a1) * h1 + dx * Bc1;
        float p = h0 * Cc0 + h1 * Cc1;
        #pragma unroll
        for (int off = 32; off > 0; off >>= 1) p += __shfl_xor(p, off, 64);
        if (ln == 0) pt[w][l] = p;
    }
    __syncthreads();

    {
        int l = ln;
        size_t idx = ((size_t)b * L_ + l) * D_ + d;
        float y = pt[w][l] + Dp[d] * xo_s[w][l];
        out_mid[idx] = (__bf16)(y * (float)xt_in[idx] + skip[idx]);
    }
}

extern "C" void kernel_launch(void* const* d_in, const int* in_sizes, int n_in,
                              void* d_out, int out_size, void* d_ws, size_t ws_size,
                              hipStream_t stream)
{
    const float* x      = (const float*)d_in[0];
    const float* proj_w = (const float*)d_in[1];
    const float* proj_b = (const float*)d_in[2];
    const float* conv_w = (const float*)d_in[3];
    const float* conv_b = (const float*)d_in[4];
    const float* dbc_w  = (const float*)d_in[5];
    const float* dt_w   = (const float*)d_in[6];
    const float* dt_b   = (const float*)d_in[7];
    const float* A_log  = (const float*)d_in[8];
    const float* Dp     = (const float*)d_in[9];
    float* out = (float*)d_out;

    __bf16* base    = (__bf16*)d_ws;
    __bf16* xp_b    = base;                   // 524288
    __bf16* xtwo_b  = xp_b + 524288;          // 524288
    __bf16* xone_b  = xtwo_b + 524288;        // 524288
    __bf16* dbc_b   = xone_b + 524288;        // 163840
    __bf16* delta_b = dbc_b + 163840;         // 524288
    __bf16* omid_b  = delta_b + 524288;       // 524288
    __bf16* pw_b    = omid_b + 524288;        // 1048576
    __bf16* dbcw_b  = pw_b + 1048576;         // 327680
    __bf16* dtw_b   = dbcw_b + 327680;        // 65536

    // 0) weights -> bf16
    prep_bf16<<<704, 256, 0, stream>>>(proj_w, dbc_w, dt_w, pw_b, dbcw_b, dtw_b);
    // 1) xp = x @ proj_w.T + b (bf16), x_two = silu(xp) (bf16)
    gemm_mfma<32, 64, 2, 2, 1, 1, 0><<<dim3(16, 16), 256, 0, stream>>>(
        x, D_, pw_b, D_, proj_b, xp_b, xtwo_b, D_, D_);
    // 2) x_one = silu(conv(xp))
    conv_silu<<<dim3(32, B_), 256, 0, stream>>>(xp_b, conv_w, conv_b, xone_b);
    // 3) dbc = x_one @ dbc_w.T
    gemm_mfma<16, 32, 1, 2, 0, 0, 0><<<dim3(10, 32), 128, 0, stream>>>(
        xone_b, D_, dbcw_b, D_, nullptr, dbc_b, nullptr, 320, D_);
    // 4) delta = softplus(dbc[:, :64] @ dt_w.T + dt_b)
    gemm_mfma<32, 64, 2, 2, 2, 0, 0><<<dim3(16, 16), 256, 0, stream>>>(
        dbc_b, 320, dtw_b, R_, dt_b, delta_b, nullptr, D_, R_);
    // 5) fused SSM scan + gating + skip
    ssm_scan<<<dim3(256, B_), 256, 0, stream>>>(
        dbc_b, delta_b, xone_b, xtwo_b, x, A_log, Dp, omid_b);
    // 6) out = out_mid @ proj_w.T + proj_b  (f32 out)
    gemm_mfma<32, 64, 2, 2, 0, 0, 1><<<dim3(16, 16), 256, 0, stream>>>(
        omid_b, D_, pw_b, D_, proj_b, out, nullptr, D_, D_);
}

// Round 5
// 186.440 us; speedup vs baseline: 1.6930x; 1.0963x over previous
//
#include <hip/hip_runtime.h>
#include <math.h>

#define B_ 8
#define L_ 64
#define D_ 1024
#define N_ 128
#define R_ 64

typedef unsigned short u16;
typedef __bf16 bf16x8 __attribute__((ext_vector_type(8)));
typedef u16 u16x8 __attribute__((ext_vector_type(8)));
typedef float floatx4 __attribute__((ext_vector_type(4)));

__device__ __forceinline__ float silu_f(float x) { return x / (1.f + __expf(-x)); }
__device__ __forceinline__ float softplus_f(float x) {
    return fmaxf(x, 0.f) + log1pf(__expf(-fabsf(x)));
}

// Convert weights to bf16 once per call. Chunks of 8 floats.
__launch_bounds__(256)
__global__ void prep_bf16(const float* __restrict__ pw,
                          const float* __restrict__ dbcw,
                          const float* __restrict__ dtw,
                          __bf16* __restrict__ pw_b,
                          __bf16* __restrict__ dbcw_b,
                          __bf16* __restrict__ dtw_b)
{
    int gid = blockIdx.x * blockDim.x + threadIdx.x;
    const float* src; __bf16* dst; int off;
    if (gid < 131072)       { src = pw;   dst = pw_b;   off = gid * 8; }
    else if (gid < 172032)  { src = dbcw; dst = dbcw_b; off = (gid - 131072) * 8; }
    else if (gid < 180224)  { src = dtw;  dst = dtw_b;  off = (gid - 172032) * 8; }
    else return;
    float4 f0 = *reinterpret_cast<const float4*>(src + off);
    float4 f1 = *reinterpret_cast<const float4*>(src + off + 4);
    bf16x8 v;
    v[0] = (__bf16)f0.x; v[1] = (__bf16)f0.y; v[2] = (__bf16)f0.z; v[3] = (__bf16)f0.w;
    v[4] = (__bf16)f1.x; v[5] = (__bf16)f1.y; v[6] = (__bf16)f1.z; v[7] = (__bf16)f1.w;
    *reinterpret_cast<bf16x8*>(dst + off) = v;
}

// C[m,n] = act( sum_k A[m,k]*W[n,k] + bias[n] )   (NT: W row-major [n][k])
// BK=64. WM*WN waves; wave tile 16 x (BN/WN); NREP = BN/WN/16.
// LDS tiles [row][64] bf16 with 16B-chunk XOR swizzle: chunk ^= (row&7).
template <int BM, int BN, int WM, int WN, int ACT, int AF32, int OUTF32>
__launch_bounds__(WM * WN * 64)
__global__ void gemm_mfma(const void* __restrict__ Ap, int lda,
                          const __bf16* __restrict__ W, int ldw,
                          const float* __restrict__ bias,
                          void* __restrict__ Cp, __bf16* __restrict__ C2,
                          int ldc, int K)
{
    constexpr int NTHR = WM * WN * 64;
    constexpr int NREP = BN / WN / 16;
    __shared__ u16 As[BM * 64];
    __shared__ u16 Bs[BN * 64];
    const int tid = threadIdx.x;
    const int l   = tid & 63;
    const int w   = tid >> 6;
    const int wm  = w / WN, wn = w % WN;
    const int m0  = blockIdx.y * BM;
    const int n0  = blockIdx.x * BN;

    floatx4 acc[NREP];
    #pragma unroll
    for (int i = 0; i < NREP; ++i) acc[i] = (floatx4)0.0f;

    for (int k0 = 0; k0 < K; k0 += 64) {
        #pragma unroll
        for (int idx = tid; idx < BM * 8; idx += NTHR) {
            int r = idx >> 3, c = idx & 7;
            u16* dst = &As[r * 64 + ((c ^ (r & 7)) * 8)];
            if (AF32) {
                const float* src = (const float*)Ap + (size_t)(m0 + r) * lda + k0 + c * 8;
                float4 f0 = *reinterpret_cast<const float4*>(src);
                float4 f1 = *reinterpret_cast<const float4*>(src + 4);
                bf16x8 v;
                v[0] = (__bf16)f0.x; v[1] = (__bf16)f0.y; v[2] = (__bf16)f0.z; v[3] = (__bf16)f0.w;
                v[4] = (__bf16)f1.x; v[5] = (__bf16)f1.y; v[6] = (__bf16)f1.z; v[7] = (__bf16)f1.w;
                *reinterpret_cast<bf16x8*>(dst) = v;
            } else {
                const u16* src = (const u16*)Ap + (size_t)(m0 + r) * lda + k0 + c * 8;
                *reinterpret_cast<u16x8*>(dst) = *reinterpret_cast<const u16x8*>(src);
            }
        }
        #pragma unroll
        for (int idx = tid; idx < BN * 8; idx += NTHR) {
            int r = idx >> 3, c = idx & 7;
            const u16* src = (const u16*)W + (size_t)(n0 + r) * ldw + k0 + c * 8;
            *reinterpret_cast<u16x8*>(&Bs[r * 64 + ((c ^ (r & 7)) * 8)]) =
                *reinterpret_cast<const u16x8*>(src);
        }
        __syncthreads();
        #pragma unroll
        for (int s = 0; s < 2; ++s) {
            const int ra = wm * 16 + (l & 15);
            const int ca = (s * 4 + (l >> 4)) ^ (ra & 7);
            bf16x8 a = *reinterpret_cast<const bf16x8*>(&As[ra * 64 + ca * 8]);
            #pragma unroll
            for (int nf = 0; nf < NREP; ++nf) {
                const int rb = wn * (BN / WN) + nf * 16 + (l & 15);
                const int cb = (s * 4 + (l >> 4)) ^ (rb & 7);
                bf16x8 b = *reinterpret_cast<const bf16x8*>(&Bs[rb * 64 + cb * 8]);
                acc[nf] = __builtin_amdgcn_mfma_f32_16x16x32_bf16(a, b, acc[nf], 0, 0, 0);
            }
        }
        __syncthreads();
    }

    #pragma unroll
    for (int nf = 0; nf < NREP; ++nf) {
        const int n = n0 + wn * (BN / WN) + nf * 16 + (l & 15);
        const float bj = bias ? bias[n] : 0.f;
        #pragma unroll
        for (int r = 0; r < 4; ++r) {
            const int m = m0 + wm * 16 + (l >> 4) * 4 + r;
            float c = acc[nf][r] + bj;
            if (ACT == 2) c = softplus_f(c);
            const size_t idx = (size_t)m * ldc + n;
            if (OUTF32) ((float*)Cp)[idx] = c;
            else        ((__bf16*)Cp)[idx] = (__bf16)c;
            if (ACT == 1) C2[idx] = (__bf16)silu_f(c);
        }
    }
}

// x_one[b,lo,d] = silu( conv_b[lo] + sum_{li,t} xp[b,li,d+t-1] * conv_w[lo,li,t] )
__launch_bounds__(256)
__global__ void conv_silu(const __bf16* __restrict__ xp,
                          const float* __restrict__ conv_w,
                          const float* __restrict__ conv_b,
                          __bf16* __restrict__ x_one)
{
    __shared__ float ws[192][65];
    __shared__ float xs[64][34];
    const int tid = threadIdx.x;
    const int b = blockIdx.y;
    const int d0 = blockIdx.x * 32;

    for (int idx = tid; idx < 64 * 64 * 3; idx += 256) {
        int lo = idx / 192, r = idx % 192;
        ws[r][lo] = conv_w[idx];
    }
    for (int idx = tid; idx < 64 * 34; idx += 256) {
        int li = idx / 34, dd = idx % 34;
        int g = d0 - 1 + dd;
        xs[li][dd] = (g >= 0 && g < D_) ? (float)xp[((size_t)b * L_ + li) * D_ + g] : 0.f;
    }
    __syncthreads();

    const int lo = tid >> 2;
    const int dbase = (tid & 3) * 8;
    float acc[8] = {};
    #pragma unroll 4
    for (int li = 0; li < 64; ++li) {
        float w0 = ws[li * 3 + 0][lo];
        float w1 = ws[li * 3 + 1][lo];
        float w2 = ws[li * 3 + 2][lo];
        float xv[10];
        #pragma unroll
        for (int j = 0; j < 10; ++j) xv[j] = xs[li][dbase + j];
        #pragma unroll
        for (int i = 0; i < 8; ++i)
            acc[i] = fmaf(w0, xv[i], fmaf(w1, xv[i + 1], fmaf(w2, xv[i + 2], acc[i])));
    }
    float bb = conv_b[lo];
    bf16x8 v;
    #pragma unroll
    for (int i = 0; i < 8; ++i) v[i] = (__bf16)silu_f(acc[i] + bb);
    *reinterpret_cast<bf16x8*>(&x_one[((size_t)b * L_ + lo) * D_ + d0 + dbase]) = v;
}

// One wave per (b,d). Lane ln owns states n=ln, n=ln+64.
// Per step: write per-lane partial p to LDS; every 16 steps transpose-reduce.
// B/C tiles of dbc staged in LDS per block (shared across the 4 waves: same b).
__launch_bounds__(256)
__global__ void ssm_scan(const __bf16* __restrict__ dbc,
                         const __bf16* __restrict__ dl_in,
                         const __bf16* __restrict__ xo_in,
                         const __bf16* __restrict__ xt_in,
                         const float* __restrict__ skip,
                         const float* __restrict__ A_log,
                         const float* __restrict__ Dp,
                         __bf16* __restrict__ out_mid)
{
    __shared__ u16 bc[64][256];       // dbc[b, l, 64..319]        (32 KB)
    __shared__ float2 dlx[4][64];     // (delta, xo) per wave      (2 KB)
    __shared__ float pt[4][16][65];   // per-wave partial tile     (16.25 KB)
    const int tid = threadIdx.x;
    const int w = tid >> 6, ln = tid & 63;
    const int b = blockIdx.y;
    const int d = blockIdx.x * 4 + w;

    // stage B/C coalesced: 2048 u16x8 chunks, 8 per thread
    {
        const u16* src = (const u16*)dbc + (size_t)b * L_ * 320;
        #pragma unroll
        for (int i = tid; i < 2048; i += 256) {
            int l = i >> 5, c = i & 31;
            *reinterpret_cast<u16x8*>(&bc[l][c * 8]) =
                *reinterpret_cast<const u16x8*>(src + l * 320 + 64 + c * 8);
        }
    }
    float dl_own = (float)dl_in[((size_t)b * L_ + ln) * D_ + d];
    float xo_own = (float)xo_in[((size_t)b * L_ + ln) * D_ + d];
    dlx[w][ln] = make_float2(dl_own, xo_own);
    const float a0 = -__expf(A_log[(size_t)d * N_ + ln]);
    const float a1 = -__expf(A_log[(size_t)d * N_ + 64 + ln]);
    __syncthreads();

    float h0 = 0.f, h1 = 0.f;
    float ych0, ych1, ych2, ych3;
    const int rr = ln & 15, qq = ln >> 4;

    #pragma unroll
    for (int c = 0; c < 4; ++c) {
        #pragma unroll
        for (int r = 0; r < 16; ++r) {
            const int l = c * 16 + r;
            float2 dd = dlx[w][l];
            float dx = dd.x * dd.y;
            float B0 = (float)*reinterpret_cast<const __bf16*>(&bc[l][ln]);
            float B1 = (float)*reinterpret_cast<const __bf16*>(&bc[l][64 + ln]);
            float C0 = (float)*reinterpret_cast<const __bf16*>(&bc[l][128 + ln]);
            float C1 = (float)*reinterpret_cast<const __bf16*>(&bc[l][192 + ln]);
            float e0 = __expf(dd.x * a0);
            float e1 = __expf(dd.x * a1);
            h0 = fmaf(e0, h0, dx * B0);
            h1 = fmaf(e1, h1, dx * B1);
            pt[w][r][ln] = fmaf(h0, C0, h1 * C1);
        }
        // transpose-reduce: lane (qq,rr) sums quarter-row rr, then combine
        float sum = 0.f;
        #pragma unroll
        for (int j = 0; j < 4; ++j) {
            float4 v = *reinterpret_cast<const float4*>(&pt[w][rr][qq * 16 + j * 4]);
            sum += (v.x + v.y) + (v.z + v.w);
        }
        sum += __shfl_xor(sum, 16, 64);
        sum += __shfl_xor(sum, 32, 64);
        if (c == 0) ych0 = sum; else if (c == 1) ych1 = sum;
        else if (c == 2) ych2 = sum; else ych3 = sum;
    }

    float ysel = (qq == 0) ? ych0 : (qq == 1) ? ych1 : (qq == 2) ? ych2 : ych3;
    size_t idx = ((size_t)b * L_ + ln) * D_ + d;
    float y = ysel + Dp[d] * xo_own;
    out_mid[idx] = (__bf16)(y * (float)xt_in[idx] + skip[idx]);
}

extern "C" void kernel_launch(void* const* d_in, const int* in_sizes, int n_in,
                              void* d_out, int out_size, void* d_ws, size_t ws_size,
                              hipStream_t stream)
{
    const float* x      = (const float*)d_in[0];
    const float* proj_w = (const float*)d_in[1];
    const float* proj_b = (const float*)d_in[2];
    const float* conv_w = (const float*)d_in[3];
    const float* conv_b = (const float*)d_in[4];
    const float* dbc_w  = (const float*)d_in[5];
    const float* dt_w   = (const float*)d_in[6];
    const float* dt_b   = (const float*)d_in[7];
    const float* A_log  = (const float*)d_in[8];
    const float* Dp     = (const float*)d_in[9];
    float* out = (float*)d_out;

    __bf16* base    = (__bf16*)d_ws;
    __bf16* xp_b    = base;                   // 524288
    __bf16* xtwo_b  = xp_b + 524288;          // 524288
    __bf16* xone_b  = xtwo_b + 524288;        // 524288
    __bf16* dbc_b   = xone_b + 524288;        // 163840
    __bf16* delta_b = dbc_b + 163840;         // 524288
    __bf16* omid_b  = delta_b + 524288;       // 524288
    __bf16* pw_b    = omid_b + 524288;        // 1048576
    __bf16* dbcw_b  = pw_b + 1048576;         // 327680
    __bf16* dtw_b   = dbcw_b + 327680;        // 65536

    // 0) weights -> bf16
    prep_bf16<<<704, 256, 0, stream>>>(proj_w, dbc_w, dt_w, pw_b, dbcw_b, dtw_b);
    // 1) xp = x @ proj_w.T + b (bf16), x_two = silu(xp) (bf16)
    gemm_mfma<32, 32, 2, 1, 1, 1, 0><<<dim3(32, 16), 128, 0, stream>>>(
        x, D_, pw_b, D_, proj_b, xp_b, xtwo_b, D_, D_);
    // 2) x_one = silu(conv(xp))
    conv_silu<<<dim3(32, B_), 256, 0, stream>>>(xp_b, conv_w, conv_b, xone_b);
    // 3) dbc = x_one @ dbc_w.T
    gemm_mfma<16, 32, 1, 2, 0, 0, 0><<<dim3(10, 32), 128, 0, stream>>>(
        xone_b, D_, dbcw_b, D_, nullptr, dbc_b, nullptr, 320, D_);
    // 4) delta = softplus(dbc[:, :64] @ dt_w.T + dt_b)
    gemm_mfma<32, 32, 2, 1, 2, 0, 0><<<dim3(32, 16), 128, 0, stream>>>(
        dbc_b, 320, dtw_b, R_, dt_b, delta_b, nullptr, D_, R_);
    // 5) fused SSM scan + gating + skip
    ssm_scan<<<dim3(256, B_), 256, 0, stream>>>(
        dbc_b, delta_b, xone_b, xtwo_b, x, A_log, Dp, omid_b);
    // 6) out = out_mid @ proj_w.T + proj_b  (f32 out)
    gemm_mfma<32, 32, 2, 1, 0, 0, 1><<<dim3(32, 16), 128, 0, stream>>>(
        omid_b, D_, pw_b, D_, proj_b, out, nullptr, D_, D_);
}

// Round 6
// 163.135 us; speedup vs baseline: 1.9349x; 1.1429x over previous
//
#include <hip/hip_runtime.h>
#include <math.h>

#define B_ 8
#define L_ 64
#define D_ 1024
#define N_ 128
#define R_ 64

typedef unsigned short u16;
typedef __bf16 bf16x8 __attribute__((ext_vector_type(8)));
typedef u16 u16x8 __attribute__((ext_vector_type(8)));
typedef float floatx4 __attribute__((ext_vector_type(4)));

__device__ __forceinline__ float silu_f(float x) { return x / (1.f + __expf(-x)); }
__device__ __forceinline__ float softplus_f(float x) {
    return fmaxf(x, 0.f) + log1pf(__expf(-fabsf(x)));
}

// f32 -> bf16: proj_w (131072 chunks), dbc_w (40960), x (65536)
__launch_bounds__(256)
__global__ void prep_bf16(const float* __restrict__ pw,
                          const float* __restrict__ dbcw,
                          const float* __restrict__ xin,
                          __bf16* __restrict__ pw_b,
                          __bf16* __restrict__ dbcw_b,
                          __bf16* __restrict__ x_b)
{
    int gid = blockIdx.x * 256 + threadIdx.x;
    const float* src; __bf16* dst; int off;
    if (gid < 131072)       { src = pw;   dst = pw_b;   off = gid * 8; }
    else if (gid < 172032)  { src = dbcw; dst = dbcw_b; off = (gid - 131072) * 8; }
    else if (gid < 237568)  { src = xin;  dst = x_b;    off = (gid - 172032) * 8; }
    else return;
    float4 f0 = *reinterpret_cast<const float4*>(src + off);
    float4 f1 = *reinterpret_cast<const float4*>(src + off + 4);
    bf16x8 v;
    v[0] = (__bf16)f0.x; v[1] = (__bf16)f0.y; v[2] = (__bf16)f0.z; v[3] = (__bf16)f0.w;
    v[4] = (__bf16)f1.x; v[5] = (__bf16)f1.y; v[6] = (__bf16)f1.z; v[7] = (__bf16)f1.w;
    *reinterpret_cast<bf16x8*>(dst + off) = v;
}

// C[m,n] = act( sum_k A[m,k]*W[n,k] + bias[n] ), A,W bf16 row-major (NT).
// Fixed: BM=32, BN=64, BK=64, 4 waves (2x2), wave tile 16x32, NREP=2.
// Reg-staged prefetch: issue loads for tile t+1 before computing tile t.
// LDS [row][64] u16, 16B-chunk swizzle: chunk ^= (row&7).
template <int ACT, int OUTF32>
__launch_bounds__(256)
__global__ void gemm_mfma(const u16* __restrict__ A, int lda,
                          const u16* __restrict__ W, int ldw,
                          const float* __restrict__ bias,
                          void* __restrict__ Cp, __bf16* __restrict__ C2,
                          int ldc, int K)
{
    __shared__ u16 As[32 * 64];
    __shared__ u16 Bs[64 * 64];
    const int tid = threadIdx.x;
    const int l   = tid & 63;
    const int w   = tid >> 6;
    const int wm  = w >> 1, wn = w & 1;
    const int m0  = blockIdx.y * 32;
    const int n0  = blockIdx.x * 64;

    const int ar = tid >> 3, ac = tid & 7;   // chunk coords (per-thread)

    u16x8 sa, sb0, sb1;
    auto issue_loads = [&](int k0) {
        sa  = *reinterpret_cast<const u16x8*>(A + (size_t)(m0 + ar) * lda + k0 + ac * 8);
        sb0 = *reinterpret_cast<const u16x8*>(W + (size_t)(n0 + ar) * ldw + k0 + ac * 8);
        sb1 = *reinterpret_cast<const u16x8*>(W + (size_t)(n0 + 32 + ar) * ldw + k0 + ac * 8);
    };
    auto stage = [&]() {
        *reinterpret_cast<u16x8*>(&As[ar * 64 + ((ac ^ (ar & 7)) * 8)]) = sa;
        *reinterpret_cast<u16x8*>(&Bs[ar * 64 + ((ac ^ (ar & 7)) * 8)]) = sb0;
        const int r2 = 32 + ar;
        *reinterpret_cast<u16x8*>(&Bs[r2 * 64 + ((ac ^ (r2 & 7)) * 8)]) = sb1;
    };

    floatx4 acc[2] = {(floatx4)0.f, (floatx4)0.f};

    issue_loads(0);
    stage();
    __syncthreads();
    const int NT = K / 64;
    for (int t = 0; t < NT; ++t) {
        if (t + 1 < NT) issue_loads((t + 1) * 64);   // prefetch: latency hides under compute
        #pragma unroll
        for (int s = 0; s < 2; ++s) {
            const int ra = wm * 16 + (l & 15);
            const int ca = (s * 4 + (l >> 4)) ^ (ra & 7);
            bf16x8 a = *reinterpret_cast<const bf16x8*>(&As[ra * 64 + ca * 8]);
            #pragma unroll
            for (int nf = 0; nf < 2; ++nf) {
                const int rb = wn * 32 + nf * 16 + (l & 15);
                const int cb = (s * 4 + (l >> 4)) ^ (rb & 7);
                bf16x8 b = *reinterpret_cast<const bf16x8*>(&Bs[rb * 64 + cb * 8]);
                acc[nf] = __builtin_amdgcn_mfma_f32_16x16x32_bf16(a, b, acc[nf], 0, 0, 0);
            }
        }
        __syncthreads();
        if (t + 1 < NT) { stage(); __syncthreads(); }
    }

    #pragma unroll
    for (int nf = 0; nf < 2; ++nf) {
        const int n = n0 + wn * 32 + nf * 16 + (l & 15);
        const float bj = bias ? bias[n] : 0.f;
        #pragma unroll
        for (int r = 0; r < 4; ++r) {
            const int m = m0 + wm * 16 + (l >> 4) * 4 + r;
            float c = acc[nf][r] + bj;
            if (ACT == 2) c = softplus_f(c);
            const size_t idx = (size_t)m * ldc + n;
            if (OUTF32) ((float*)Cp)[idx] = c;
            else        ((__bf16*)Cp)[idx] = (__bf16)c;
            if (ACT == 1) C2[idx] = (__bf16)silu_f(c);
        }
    }
}

// x_one[b,lo,d] = silu( conv_b[lo] + sum_{li,t} xp[b,li,d+t-1] * conv_w[lo,li,t] )
__launch_bounds__(256)
__global__ void conv_silu(const __bf16* __restrict__ xp,
                          const float* __restrict__ conv_w,
                          const float* __restrict__ conv_b,
                          __bf16* __restrict__ x_one)
{
    __shared__ float ws[192][65];
    __shared__ float xs[64][34];
    const int tid = threadIdx.x;
    const int b = blockIdx.y;
    const int d0 = blockIdx.x * 32;

    for (int idx = tid; idx < 64 * 64 * 3; idx += 256) {
        int lo = idx / 192, r = idx % 192;
        ws[r][lo] = conv_w[idx];
    }
    for (int idx = tid; idx < 64 * 34; idx += 256) {
        int li = idx / 34, dd = idx % 34;
        int g = d0 - 1 + dd;
        xs[li][dd] = (g >= 0 && g < D_) ? (float)xp[((size_t)b * L_ + li) * D_ + g] : 0.f;
    }
    __syncthreads();

    const int lo = tid >> 2;
    const int dbase = (tid & 3) * 8;
    float acc[8] = {};
    #pragma unroll 4
    for (int li = 0; li < 64; ++li) {
        float w0 = ws[li * 3 + 0][lo];
        float w1 = ws[li * 3 + 1][lo];
        float w2 = ws[li * 3 + 2][lo];
        float xv[10];
        #pragma unroll
        for (int j = 0; j < 10; ++j) xv[j] = xs[li][dbase + j];
        #pragma unroll
        for (int i = 0; i < 8; ++i)
            acc[i] = fmaf(w0, xv[i], fmaf(w1, xv[i + 1], fmaf(w2, xv[i + 2], acc[i])));
    }
    float bb = conv_b[lo];
    bf16x8 v;
    #pragma unroll
    for (int i = 0; i < 8; ++i) v[i] = (__bf16)silu_f(acc[i] + bb);
    *reinterpret_cast<bf16x8*>(&x_one[((size_t)b * L_ + lo) * D_ + d0 + dbase]) = v;
}

// One wave per (b,d). Lane ln owns states n=ln, n=ln+64.
// Fused: delta = softplus(dbc[:, :64] @ dt_w[d].T + dt_b[d]) computed in-block
// (thread (w,ln) does the 64-FMA dot for l=ln with diagonal k-offset).
// Scan: per-step partial p -> LDS; transpose-reduce every 16 steps.
__launch_bounds__(256)
__global__ void ssm_scan(const __bf16* __restrict__ dbc,
                         const float* __restrict__ dt_w,
                         const float* __restrict__ dt_b,
                         const __bf16* __restrict__ xo_in,
                         const __bf16* __restrict__ xt_in,
                         const float* __restrict__ skip,
                         const float* __restrict__ A_log,
                         const float* __restrict__ Dp,
                         __bf16* __restrict__ out_mid)
{
    __shared__ u16 bcs[64][320];      // dbc[b, l, 0..319]   (40 KB)
    __shared__ float dtw_s[4][64];    // dt_w rows for the 4 d's (1 KB)
    __shared__ float2 dlx[4][64];     // (delta, xo) per wave (2 KB)
    __shared__ float pt[4][16][65];   // partial tile        (16.25 KB)
    const int tid = threadIdx.x;
    const int w = tid >> 6, ln = tid & 63;
    const int b = blockIdx.y;
    const int d = blockIdx.x * 4 + w;

    {   // stage full dbc[b] : 64 rows x 40 chunks = 2560 chunks, 10/thread
        const u16* src = (const u16*)dbc + (size_t)b * L_ * 320;
        #pragma unroll
        for (int i = tid; i < 2560; i += 256) {
            int lr = i / 40, c = i % 40;
            *reinterpret_cast<u16x8*>(&bcs[lr][c * 8]) =
                *reinterpret_cast<const u16x8*>(src + lr * 320 + c * 8);
        }
    }
    dtw_s[w][ln] = dt_w[(size_t)d * 64 + ln];
    const float xo_own = (float)xo_in[((size_t)b * L_ + ln) * D_ + d];
    const float a0 = -__expf(A_log[(size_t)d * N_ + ln]);
    const float a1 = -__expf(A_log[(size_t)d * N_ + 64 + ln]);
    const float dtb = dt_b[d];
    __syncthreads();

    // delta(l=ln, d): 64-FMA dot, diagonal start kills bank conflicts
    float accd = dtb;
    #pragma unroll
    for (int k = 0; k < 64; ++k) {
        int kk = (k + ln) & 63;
        accd = fmaf((float)*reinterpret_cast<const __bf16*>(&bcs[ln][kk]),
                    dtw_s[w][kk], accd);
    }
    const float dl_own = softplus_f(accd);
    dlx[w][ln] = make_float2(dl_own, xo_own);
    __syncthreads();

    float h0 = 0.f, h1 = 0.f;
    float ych[4];
    const int rr = ln & 15, qq = ln >> 4;

    #pragma unroll
    for (int cch = 0; cch < 4; ++cch) {
        #pragma unroll
        for (int r = 0; r < 16; ++r) {
            const int l = cch * 16 + r;
            float2 dd = dlx[w][l];
            float dx = dd.x * dd.y;
            float B0 = (float)*reinterpret_cast<const __bf16*>(&bcs[l][64 + ln]);
            float B1 = (float)*reinterpret_cast<const __bf16*>(&bcs[l][128 + ln]);
            float C0 = (float)*reinterpret_cast<const __bf16*>(&bcs[l][192 + ln]);
            float C1 = (float)*reinterpret_cast<const __bf16*>(&bcs[l][256 + ln]);
            h0 = fmaf(__expf(dd.x * a0), h0, dx * B0);
            h1 = fmaf(__expf(dd.x * a1), h1, dx * B1);
            pt[w][r][ln] = fmaf(h0, C0, h1 * C1);
        }
        float sum = 0.f;
        #pragma unroll
        for (int j = 0; j < 4; ++j) {
            float4 v = *reinterpret_cast<const float4*>(&pt[w][rr][qq * 16 + j * 4]);
            sum += (v.x + v.y) + (v.z + v.w);
        }
        sum += __shfl_xor(sum, 16, 64);
        sum += __shfl_xor(sum, 32, 64);
        ych[cch] = sum;
    }

    float ysel = (qq == 0) ? ych[0] : (qq == 1) ? ych[1] : (qq == 2) ? ych[2] : ych[3];
    size_t idx = ((size_t)b * L_ + ln) * D_ + d;
    float y = ysel + Dp[d] * xo_own;
    out_mid[idx] = (__bf16)(y * (float)xt_in[idx] + skip[idx]);
}

extern "C" void kernel_launch(void* const* d_in, const int* in_sizes, int n_in,
                              void* d_out, int out_size, void* d_ws, size_t ws_size,
                              hipStream_t stream)
{
    const float* x      = (const float*)d_in[0];
    const float* proj_w = (const float*)d_in[1];
    const float* proj_b = (const float*)d_in[2];
    const float* conv_w = (const float*)d_in[3];
    const float* conv_b = (const float*)d_in[4];
    const float* dbc_w  = (const float*)d_in[5];
    const float* dt_w   = (const float*)d_in[6];
    const float* dt_b   = (const float*)d_in[7];
    const float* A_log  = (const float*)d_in[8];
    const float* Dp     = (const float*)d_in[9];
    float* out = (float*)d_out;

    __bf16* base    = (__bf16*)d_ws;
    __bf16* xp_b    = base;                   // 524288
    __bf16* xtwo_b  = xp_b + 524288;          // 524288
    __bf16* xone_b  = xtwo_b + 524288;        // 524288
    __bf16* dbc_b   = xone_b + 524288;        // 163840
    __bf16* omid_b  = dbc_b + 163840;         // 524288
    __bf16* pw_b    = omid_b + 524288;        // 1048576
    __bf16* dbcw_b  = pw_b + 1048576;         // 327680
    __bf16* x_b     = dbcw_b + 327680;        // 524288

    // 0) f32 -> bf16 (weights + x)
    prep_bf16<<<928, 256, 0, stream>>>(proj_w, dbc_w, x, pw_b, dbcw_b, x_b);
    // 1) xp = x @ proj_w.T + b (bf16), x_two = silu(xp)
    gemm_mfma<1, 0><<<dim3(16, 16), 256, 0, stream>>>(
        (const u16*)x_b, D_, (const u16*)pw_b, D_, proj_b, xp_b, xtwo_b, D_, D_);
    // 2) x_one = silu(conv(xp))
    conv_silu<<<dim3(32, B_), 256, 0, stream>>>(xp_b, conv_w, conv_b, xone_b);
    // 3) dbc = x_one @ dbc_w.T   (N = 320)
    gemm_mfma<0, 0><<<dim3(5, 16), 256, 0, stream>>>(
        (const u16*)xone_b, D_, (const u16*)dbcw_b, D_, nullptr, dbc_b, nullptr, 320, D_);
    // 4+5) fused delta-GEMM + SSM scan + gating + skip
    ssm_scan<<<dim3(256, B_), 256, 0, stream>>>(
        dbc_b, dt_w, dt_b, xone_b, xtwo_b, x, A_log, Dp, omid_b);
    // 6) out = out_mid @ proj_w.T + proj_b  (f32 out)
    gemm_mfma<0, 1><<<dim3(16, 16), 256, 0, stream>>>(
        (const u16*)omid_b, D_, (const u16*)pw_b, D_, proj_b, out, nullptr, D_, D_);
}

// Round 7
// 156.714 us; speedup vs baseline: 2.0142x; 1.0410x over previous
//
#include <hip/hip_runtime.h>
#include <math.h>

#define B_ 8
#define L_ 64
#define D_ 1024
#define N_ 128
#define R_ 64

typedef unsigned short u16;
typedef __bf16 bf16x8 __attribute__((ext_vector_type(8)));
typedef u16 u16x8 __attribute__((ext_vector_type(8)));
typedef float floatx4 __attribute__((ext_vector_type(4)));

__device__ __forceinline__ float silu_f(float x) { return x / (1.f + __expf(-x)); }
__device__ __forceinline__ float softplus_f(float x) {
    return fmaxf(x, 0.f) + log1pf(__expf(-fabsf(x)));
}

// f32 -> bf16: proj_w (131072 chunks), dbc_w (40960), x (65536)
__launch_bounds__(256)
__global__ void prep_bf16(const float* __restrict__ pw,
                          const float* __restrict__ dbcw,
                          const float* __restrict__ xin,
                          __bf16* __restrict__ pw_b,
                          __bf16* __restrict__ dbcw_b,
                          __bf16* __restrict__ x_b)
{
    int gid = blockIdx.x * 256 + threadIdx.x;
    const float* src; __bf16* dst; int off;
    if (gid < 131072)       { src = pw;   dst = pw_b;   off = gid * 8; }
    else if (gid < 172032)  { src = dbcw; dst = dbcw_b; off = (gid - 131072) * 8; }
    else if (gid < 237568)  { src = xin;  dst = x_b;    off = (gid - 172032) * 8; }
    else return;
    float4 f0 = *reinterpret_cast<const float4*>(src + off);
    float4 f1 = *reinterpret_cast<const float4*>(src + off + 4);
    bf16x8 v;
    v[0] = (__bf16)f0.x; v[1] = (__bf16)f0.y; v[2] = (__bf16)f0.z; v[3] = (__bf16)f0.w;
    v[4] = (__bf16)f1.x; v[5] = (__bf16)f1.y; v[6] = (__bf16)f1.z; v[7] = (__bf16)f1.w;
    *reinterpret_cast<bf16x8*>(dst + off) = v;
}

// C[m,n] = act( sum_k A[m,k]*W[n,k] + bias[n] ), A,W bf16 row-major (NT).
// Wave tile 16 x (BN/WN). Double-buffered LDS (1 barrier / K-tile),
// reg-staged prefetch (issue early / stage late). Swizzle: chunk ^= row&7.
// ACT: 0 none, 1 raw->C + silu->C2, 2 softplus.
// SPLIT: dbc mode. Cp = dR (delta cols, row-major [m][64]),
//        C2 = bct (B/C cols transposed [b][n-64][l]).
template <int BM, int BN, int WM, int WN, int ACT, int OUTF32, int SPLIT>
__launch_bounds__(WM * WN * 64)
__global__ void gemm_mfma(const u16* __restrict__ A, int lda,
                          const u16* __restrict__ W, int ldw,
                          const float* __restrict__ bias,
                          void* __restrict__ Cp, __bf16* __restrict__ C2,
                          int ldc, int K)
{
    constexpr int NTHR = WM * WN * 64;
    constexpr int NREP = BN / WN / 16;
    constexpr int NA = BM * 8 / NTHR;
    constexpr int NB = BN * 8 / NTHR;
    __shared__ u16 As[2][BM * 64];
    __shared__ u16 Bs[2][BN * 64];
    const int tid = threadIdx.x;
    const int l   = tid & 63;
    const int w   = tid >> 6;
    const int wm  = w / WN, wn = w % WN;
    const int m0  = blockIdx.y * BM;
    const int n0  = blockIdx.x * BN;

    u16x8 sa[NA], sb[NB];
    auto issue_loads = [&](int k0) {
        #pragma unroll
        for (int i = 0; i < NA; ++i) {
            int idx = tid + i * NTHR, r = idx >> 3, c = idx & 7;
            sa[i] = *reinterpret_cast<const u16x8*>(A + (size_t)(m0 + r) * lda + k0 + c * 8);
        }
        #pragma unroll
        for (int i = 0; i < NB; ++i) {
            int idx = tid + i * NTHR, r = idx >> 3, c = idx & 7;
            sb[i] = *reinterpret_cast<const u16x8*>(W + (size_t)(n0 + r) * ldw + k0 + c * 8);
        }
    };
    auto stage = [&](int bb) {
        #pragma unroll
        for (int i = 0; i < NA; ++i) {
            int idx = tid + i * NTHR, r = idx >> 3, c = idx & 7;
            *reinterpret_cast<u16x8*>(&As[bb][r * 64 + ((c ^ (r & 7)) * 8)]) = sa[i];
        }
        #pragma unroll
        for (int i = 0; i < NB; ++i) {
            int idx = tid + i * NTHR, r = idx >> 3, c = idx & 7;
            *reinterpret_cast<u16x8*>(&Bs[bb][r * 64 + ((c ^ (r & 7)) * 8)]) = sb[i];
        }
    };

    floatx4 acc[NREP];
    #pragma unroll
    for (int i = 0; i < NREP; ++i) acc[i] = (floatx4)0.f;

    issue_loads(0);
    stage(0);
    __syncthreads();
    const int NT = K / 64;
    for (int t = 0; t < NT; ++t) {
        if (t + 1 < NT) issue_loads((t + 1) * 64);
        const int bb = t & 1;
        #pragma unroll
        for (int s = 0; s < 2; ++s) {
            const int ra = wm * 16 + (l & 15);
            const int ca = (s * 4 + (l >> 4)) ^ (ra & 7);
            bf16x8 a = *reinterpret_cast<const bf16x8*>(&As[bb][ra * 64 + ca * 8]);
            #pragma unroll
            for (int nf = 0; nf < NREP; ++nf) {
                const int rb = wn * (BN / WN) + nf * 16 + (l & 15);
                const int cb = (s * 4 + (l >> 4)) ^ (rb & 7);
                bf16x8 b = *reinterpret_cast<const bf16x8*>(&Bs[bb][rb * 64 + cb * 8]);
                acc[nf] = __builtin_amdgcn_mfma_f32_16x16x32_bf16(a, b, acc[nf], 0, 0, 0);
            }
        }
        if (t + 1 < NT) { stage((t + 1) & 1); __syncthreads(); }
    }

    #pragma unroll
    for (int nf = 0; nf < NREP; ++nf) {
        const int n = n0 + wn * (BN / WN) + nf * 16 + (l & 15);
        const float bj = bias ? bias[n] : 0.f;
        #pragma unroll
        for (int r = 0; r < 4; ++r) {
            const int m = m0 + wm * 16 + (l >> 4) * 4 + r;
            float c = acc[nf][r] + bj;
            if (ACT == 2) c = softplus_f(c);
            if (SPLIT) {
                if (n0 < 64) ((__bf16*)Cp)[(size_t)m * 64 + n] = (__bf16)c;
                else {
                    const int bb2 = m >> 6, ll = m & 63;
                    C2[((size_t)bb2 * 256 + (n - 64)) * 64 + ll] = (__bf16)c;
                }
            } else {
                const size_t idx = (size_t)m * ldc + n;
                if (OUTF32) ((float*)Cp)[idx] = c;
                else        ((__bf16*)Cp)[idx] = (__bf16)c;
                if (ACT == 1) C2[idx] = (__bf16)silu_f(c);
            }
        }
    }
}

// x_one[b,lo,d] = silu( conv_b[lo] + sum_{li,t} xp[b,li,d+t-1] * conv_w[lo,li,t] )
__launch_bounds__(256)
__global__ void conv_silu(const __bf16* __restrict__ xp,
                          const float* __restrict__ conv_w,
                          const float* __restrict__ conv_b,
                          __bf16* __restrict__ x_one)
{
    __shared__ float ws[192][65];
    __shared__ float xs[64][34];
    const int tid = threadIdx.x;
    const int b = blockIdx.y;
    const int d0 = blockIdx.x * 32;

    for (int idx = tid; idx < 64 * 64 * 3; idx += 256) {
        int lo = idx / 192, r = idx % 192;
        ws[r][lo] = conv_w[idx];
    }
    for (int idx = tid; idx < 64 * 34; idx += 256) {
        int li = idx / 34, dd = idx % 34;
        int g = d0 - 1 + dd;
        xs[li][dd] = (g >= 0 && g < D_) ? (float)xp[((size_t)b * L_ + li) * D_ + g] : 0.f;
    }
    __syncthreads();

    const int lo = tid >> 2;
    const int dbase = (tid & 3) * 8;
    float acc[8] = {};
    #pragma unroll 4
    for (int li = 0; li < 64; ++li) {
        float w0 = ws[li * 3 + 0][lo];
        float w1 = ws[li * 3 + 1][lo];
        float w2 = ws[li * 3 + 2][lo];
        float xv[10];
        #pragma unroll
        for (int j = 0; j < 10; ++j) xv[j] = xs[li][dbase + j];
        #pragma unroll
        for (int i = 0; i < 8; ++i)
            acc[i] = fmaf(w0, xv[i], fmaf(w1, xv[i + 1], fmaf(w2, xv[i + 2], acc[i])));
    }
    float bb = conv_b[lo];
    bf16x8 v;
    #pragma unroll
    for (int i = 0; i < 8; ++i) v[i] = (__bf16)silu_f(acc[i] + bb);
    *reinterpret_cast<bf16x8*>(&x_one[((size_t)b * L_ + lo) * D_ + d0 + dbase]) = v;
}

// One wave per (b,d). Lane ln owns states n=ln, n=ln+64.
// B/C come in TRANSPOSED (bct[b][j][l], j = col-64): per-8-step chunk each lane
// preloads B0/B1/C0/C1 rows as one ds_read_b128 each -> register extracts.
// Delta: fused softplus(dR[l] . dt_w[d] + dt_b[d]) per thread.
__launch_bounds__(256)
__global__ void ssm_scan(const __bf16* __restrict__ dR,
                         const __bf16* __restrict__ bct,
                         const float* __restrict__ dt_w,
                         const float* __restrict__ dt_b,
                         const __bf16* __restrict__ xo_in,
                         const __bf16* __restrict__ xt_in,
                         const float* __restrict__ skip,
                         const float* __restrict__ A_log,
                         const float* __restrict__ Dp,
                         __bf16* __restrict__ out_mid)
{
    __shared__ u16 bcts[256 * 66];    // 33792 B (pad 66: 2-way max)
    __shared__ u16 dRs[64 * 66];      // 8448 B
    __shared__ float dtw_s[4][64];    // 1024 B
    __shared__ float2 dlx[4][64];     // 2048 B
    __shared__ float pt[4][8][68];    // 8704 B   (total ~54 KB -> 3 blocks/CU)
    const int tid = threadIdx.x;
    const int w = tid >> 6, ln = tid & 63;
    const int b = blockIdx.y;
    const int d = blockIdx.x * 4 + w;

    {   // stage bct[b]: 256 rows x 8 chunks, coalesced
        const u16* src = (const u16*)bct + (size_t)b * 256 * 64;
        #pragma unroll
        for (int i = tid; i < 2048; i += 256) {
            int n = i >> 3, c = i & 7;
            *reinterpret_cast<u16x8*>(&bcts[n * 66 + c * 8]) =
                *reinterpret_cast<const u16x8*>(src + n * 64 + c * 8);
        }
        // stage dR[b]: 64 rows x 8 chunks
        const u16* srcd = (const u16*)dR + (size_t)b * 64 * 64;
        #pragma unroll
        for (int i = tid; i < 512; i += 256) {
            int r = i >> 3, c = i & 7;
            *reinterpret_cast<u16x8*>(&dRs[r * 66 + c * 8]) =
                *reinterpret_cast<const u16x8*>(srcd + r * 64 + c * 8);
        }
    }
    dtw_s[w][ln] = dt_w[(size_t)d * 64 + ln];
    const float xo_own = (float)xo_in[((size_t)b * L_ + ln) * D_ + d];
    const float a0 = -__expf(A_log[(size_t)d * N_ + ln]);
    const float a1 = -__expf(A_log[(size_t)d * N_ + 64 + ln]);
    const float dtb = dt_b[d];
    __syncthreads();

    // delta(l=ln, d): 64-FMA dot, diagonal k-offset
    float accd = dtb;
    #pragma unroll
    for (int k = 0; k < 64; ++k) {
        int kk = (k + ln) & 63;
        accd = fmaf((float)*reinterpret_cast<const __bf16*>(&dRs[ln * 66 + kk]),
                    dtw_s[w][kk], accd);
    }
    const float dl_own = softplus_f(accd);
    dlx[w][ln] = make_float2(dl_own, xo_own);
    __syncthreads();

    float h0 = 0.f, h1 = 0.f, y_own = 0.f;
    const int rr = ln & 7, qs = ln >> 3;

    #pragma unroll
    for (int cc = 0; cc < 8; ++cc) {
        bf16x8 B0r = *reinterpret_cast<const bf16x8*>(&bcts[(      ln) * 66 + cc * 8]);
        bf16x8 B1r = *reinterpret_cast<const bf16x8*>(&bcts[( 64 + ln) * 66 + cc * 8]);
        bf16x8 C0r = *reinterpret_cast<const bf16x8*>(&bcts[(128 + ln) * 66 + cc * 8]);
        bf16x8 C1r = *reinterpret_cast<const bf16x8*>(&bcts[(192 + ln) * 66 + cc * 8]);
        #pragma unroll
        for (int r = 0; r < 8; ++r) {
            const int l = cc * 8 + r;
            float2 dd = dlx[w][l];
            float dx = dd.x * dd.y;
            h0 = fmaf(__expf(dd.x * a0), h0, dx * (float)B0r[r]);
            h1 = fmaf(__expf(dd.x * a1), h1, dx * (float)B1r[r]);
            pt[w][r][ln] = fmaf(h0, (float)C0r[r], h1 * (float)C1r[r]);
        }
        float sum = 0.f;
        #pragma unroll
        for (int j = 0; j < 2; ++j) {
            float4 v = *reinterpret_cast<const float4*>(&pt[w][rr][qs * 8 + j * 4]);
            sum += (v.x + v.y) + (v.z + v.w);
        }
        sum += __shfl_xor(sum, 8, 64);
        sum += __shfl_xor(sum, 16, 64);
        sum += __shfl_xor(sum, 32, 64);
        if ((ln >> 3) == cc) y_own = sum;   // l = cc*8 + (ln&7) == ln
    }

    size_t idx = ((size_t)b * L_ + ln) * D_ + d;
    float y = y_own + Dp[d] * xo_own;
    out_mid[idx] = (__bf16)(y * (float)xt_in[idx] + skip[idx]);
}

extern "C" void kernel_launch(void* const* d_in, const int* in_sizes, int n_in,
                              void* d_out, int out_size, void* d_ws, size_t ws_size,
                              hipStream_t stream)
{
    const float* x      = (const float*)d_in[0];
    const float* proj_w = (const float*)d_in[1];
    const float* proj_b = (const float*)d_in[2];
    const float* conv_w = (const float*)d_in[3];
    const float* conv_b = (const float*)d_in[4];
    const float* dbc_w  = (const float*)d_in[5];
    const float* dt_w   = (const float*)d_in[6];
    const float* dt_b   = (const float*)d_in[7];
    const float* A_log  = (const float*)d_in[8];
    const float* Dp     = (const float*)d_in[9];
    float* out = (float*)d_out;

    __bf16* base    = (__bf16*)d_ws;
    __bf16* xp_b    = base;                   // 524288
    __bf16* xtwo_b  = xp_b + 524288;          // 524288
    __bf16* xone_b  = xtwo_b + 524288;        // 524288
    __bf16* dR_b    = xone_b + 524288;        // 32768   [b][l][64]
    __bf16* bct_b   = dR_b + 32768;           // 131072  [b][j][l]
    __bf16* omid_b  = bct_b + 131072;         // 524288
    __bf16* pw_b    = omid_b + 524288;        // 1048576
    __bf16* dbcw_b  = pw_b + 1048576;         // 327680
    __bf16* x_b     = dbcw_b + 327680;        // 524288

    // 0) f32 -> bf16 (weights + x)
    prep_bf16<<<928, 256, 0, stream>>>(proj_w, dbc_w, x, pw_b, dbcw_b, x_b);
    // 1) xp = x @ proj_w.T + b (bf16), x_two = silu(xp)
    gemm_mfma<32, 32, 2, 2, 1, 0, 0><<<dim3(32, 16), 256, 0, stream>>>(
        (const u16*)x_b, D_, (const u16*)pw_b, D_, proj_b, xp_b, xtwo_b, D_, D_);
    // 2) x_one = silu(conv(xp))
    conv_silu<<<dim3(32, B_), 256, 0, stream>>>(xp_b, conv_w, conv_b, xone_b);
    // 3) dbc = x_one @ dbc_w.T, split-written: dR row-major, bct transposed
    gemm_mfma<16, 32, 1, 2, 0, 0, 1><<<dim3(10, 32), 128, 0, stream>>>(
        (const u16*)xone_b, D_, (const u16*)dbcw_b, D_, nullptr, dR_b, bct_b, 320, D_);
    // 4+5) fused delta-GEMM + SSM scan + gating + skip
    ssm_scan<<<dim3(256, B_), 256, 0, stream>>>(
        dR_b, bct_b, dt_w, dt_b, xone_b, xtwo_b, x, A_log, Dp, omid_b);
    // 6) out = out_mid @ proj_w.T + proj_b  (f32 out)
    gemm_mfma<32, 32, 2, 2, 0, 1, 0><<<dim3(32, 16), 256, 0, stream>>>(
        (const u16*)omid_b, D_, (const u16*)pw_b, D_, proj_b, out, nullptr, D_, D_);
}

// Round 8
// 136.514 us; speedup vs baseline: 2.3122x; 1.1480x over previous
//
#include <hip/hip_runtime.h>
#include <math.h>

#define B_ 8
#define L_ 64
#define D_ 1024
#define N_ 128
#define R_ 64

typedef unsigned short u16;
typedef __bf16 bf16x8 __attribute__((ext_vector_type(8)));
typedef u16 u16x8 __attribute__((ext_vector_type(8)));
typedef float floatx4 __attribute__((ext_vector_type(4)));

__device__ __forceinline__ float silu_f(float x) { return x / (1.f + __expf(-x)); }
__device__ __forceinline__ float softplus_f(float x) {
    return fmaxf(x, 0.f) + log1pf(__expf(-fabsf(x)));
}

// f32 -> bf16: proj_w (131072 chunks), dbc_w (40960), x (65536)
__launch_bounds__(256)
__global__ void prep_bf16(const float* __restrict__ pw,
                          const float* __restrict__ dbcw,
                          const float* __restrict__ xin,
                          __bf16* __restrict__ pw_b,
                          __bf16* __restrict__ dbcw_b,
                          __bf16* __restrict__ x_b)
{
    int gid = blockIdx.x * 256 + threadIdx.x;
    const float* src; __bf16* dst; int off;
    if (gid < 131072)       { src = pw;   dst = pw_b;   off = gid * 8; }
    else if (gid < 172032)  { src = dbcw; dst = dbcw_b; off = (gid - 131072) * 8; }
    else if (gid < 237568)  { src = xin;  dst = x_b;    off = (gid - 172032) * 8; }
    else return;
    float4 f0 = *reinterpret_cast<const float4*>(src + off);
    float4 f1 = *reinterpret_cast<const float4*>(src + off + 4);
    bf16x8 v;
    v[0] = (__bf16)f0.x; v[1] = (__bf16)f0.y; v[2] = (__bf16)f0.z; v[3] = (__bf16)f0.w;
    v[4] = (__bf16)f1.x; v[5] = (__bf16)f1.y; v[6] = (__bf16)f1.z; v[7] = (__bf16)f1.w;
    *reinterpret_cast<bf16x8*>(dst + off) = v;
}

// C[m,n] = act( sum_k A[m,k]*W[n,k] + bias[n] ), A,W bf16 row-major (NT).
// BK=128, double-buffered LDS (1 barrier / K-tile), reg-staged prefetch.
// LDS row = 128 u16 (16 chunks of 8); swizzle: chunk ^= (row&7)<<1.
// ACT: 0 none, 1 raw->C + silu->C2, 2 softplus.
// SPLIT: dbc mode. Cp = dR ([b*64+l][64] row-major), C2 = bct ([b][n-64][l]).
template <int BM, int BN, int WM, int WN, int ACT, int OUTF32, int SPLIT>
__launch_bounds__(WM * WN * 64)
__global__ void gemm_mfma(const u16* __restrict__ A, int lda,
                          const u16* __restrict__ W, int ldw,
                          const float* __restrict__ bias,
                          void* __restrict__ Cp, __bf16* __restrict__ C2,
                          int ldc, int K)
{
    constexpr int NTHR = WM * WN * 64;
    constexpr int NREP = BN / WN / 16;
    constexpr int NA = BM * 16 / NTHR;
    constexpr int NB = BN * 16 / NTHR;
    __shared__ u16 As[2][BM * 128];
    __shared__ u16 Bs[2][BN * 128];
    const int tid = threadIdx.x;
    const int l   = tid & 63;
    const int w   = tid >> 6;
    const int wm  = w / WN, wn = w % WN;
    const int m0  = blockIdx.y * BM;
    const int n0  = blockIdx.x * BN;

    u16x8 sa[NA], sb[NB];
    auto issue_loads = [&](int k0) {
        #pragma unroll
        for (int i = 0; i < NA; ++i) {
            int idx = tid + i * NTHR, r = idx >> 4, c = idx & 15;
            sa[i] = *reinterpret_cast<const u16x8*>(A + (size_t)(m0 + r) * lda + k0 + c * 8);
        }
        #pragma unroll
        for (int i = 0; i < NB; ++i) {
            int idx = tid + i * NTHR, r = idx >> 4, c = idx & 15;
            sb[i] = *reinterpret_cast<const u16x8*>(W + (size_t)(n0 + r) * ldw + k0 + c * 8);
        }
    };
    auto stage = [&](int bb) {
        #pragma unroll
        for (int i = 0; i < NA; ++i) {
            int idx = tid + i * NTHR, r = idx >> 4, c = idx & 15;
            *reinterpret_cast<u16x8*>(&As[bb][r * 128 + ((c ^ ((r & 7) << 1)) * 8)]) = sa[i];
        }
        #pragma unroll
        for (int i = 0; i < NB; ++i) {
            int idx = tid + i * NTHR, r = idx >> 4, c = idx & 15;
            *reinterpret_cast<u16x8*>(&Bs[bb][r * 128 + ((c ^ ((r & 7) << 1)) * 8)]) = sb[i];
        }
    };

    floatx4 acc[NREP];
    #pragma unroll
    for (int i = 0; i < NREP; ++i) acc[i] = (floatx4)0.f;

    issue_loads(0);
    stage(0);
    __syncthreads();
    const int NT = K / 128;
    for (int t = 0; t < NT; ++t) {
        if (t + 1 < NT) issue_loads((t + 1) * 128);
        const int bb = t & 1;
        #pragma unroll
        for (int s = 0; s < 4; ++s) {
            const int ra = wm * 16 + (l & 15);
            const int ca = (s * 4 + (l >> 4)) ^ ((ra & 7) << 1);
            bf16x8 a = *reinterpret_cast<const bf16x8*>(&As[bb][ra * 128 + ca * 8]);
            #pragma unroll
            for (int nf = 0; nf < NREP; ++nf) {
                const int rb = wn * (BN / WN) + nf * 16 + (l & 15);
                const int cb = (s * 4 + (l >> 4)) ^ ((rb & 7) << 1);
                bf16x8 b = *reinterpret_cast<const bf16x8*>(&Bs[bb][rb * 128 + cb * 8]);
                acc[nf] = __builtin_amdgcn_mfma_f32_16x16x32_bf16(a, b, acc[nf], 0, 0, 0);
            }
        }
        if (t + 1 < NT) { stage((t + 1) & 1); __syncthreads(); }
    }

    #pragma unroll
    for (int nf = 0; nf < NREP; ++nf) {
        const int n = n0 + wn * (BN / WN) + nf * 16 + (l & 15);
        const float bj = bias ? bias[n] : 0.f;
        #pragma unroll
        for (int r = 0; r < 4; ++r) {
            const int m = m0 + wm * 16 + (l >> 4) * 4 + r;
            float c = acc[nf][r] + bj;
            if (ACT == 2) c = softplus_f(c);
            if (SPLIT) {
                if (n0 < 64) ((__bf16*)Cp)[(size_t)m * 64 + n] = (__bf16)c;
                else {
                    const int bb2 = m >> 6, ll = m & 63;
                    C2[((size_t)bb2 * 256 + (n - 64)) * 64 + ll] = (__bf16)c;
                }
            } else {
                const size_t idx = (size_t)m * ldc + n;
                if (OUTF32) ((float*)Cp)[idx] = c;
                else        ((__bf16*)Cp)[idx] = (__bf16)c;
                if (ACT == 1) C2[idx] = (__bf16)silu_f(c);
            }
        }
    }
}

// x_one[b,lo,d] = silu( conv_b[lo] + sum_{li,t} xp[b,li,d+t-1] * conv_w[lo,li,t] )
__launch_bounds__(256)
__global__ void conv_silu(const __bf16* __restrict__ xp,
                          const float* __restrict__ conv_w,
                          const float* __restrict__ conv_b,
                          __bf16* __restrict__ x_one)
{
    __shared__ float ws[192][65];
    __shared__ float xs[64][34];
    const int tid = threadIdx.x;
    const int b = blockIdx.y;
    const int d0 = blockIdx.x * 32;

    for (int idx = tid; idx < 64 * 64 * 3; idx += 256) {
        int lo = idx / 192, r = idx % 192;
        ws[r][lo] = conv_w[idx];
    }
    for (int idx = tid; idx < 64 * 34; idx += 256) {
        int li = idx / 34, dd = idx % 34;
        int g = d0 - 1 + dd;
        xs[li][dd] = (g >= 0 && g < D_) ? (float)xp[((size_t)b * L_ + li) * D_ + g] : 0.f;
    }
    __syncthreads();

    const int lo = tid >> 2;
    const int dbase = (tid & 3) * 8;
    float acc[8] = {};
    #pragma unroll 4
    for (int li = 0; li < 64; ++li) {
        float w0 = ws[li * 3 + 0][lo];
        float w1 = ws[li * 3 + 1][lo];
        float w2 = ws[li * 3 + 2][lo];
        float xv[10];
        #pragma unroll
        for (int j = 0; j < 10; ++j) xv[j] = xs[li][dbase + j];
        #pragma unroll
        for (int i = 0; i < 8; ++i)
            acc[i] = fmaf(w0, xv[i], fmaf(w1, xv[i + 1], fmaf(w2, xv[i + 2], acc[i])));
    }
    float bb = conv_b[lo];
    bf16x8 v;
    #pragma unroll
    for (int i = 0; i < 8; ++i) v[i] = (__bf16)silu_f(acc[i] + bb);
    *reinterpret_cast<bf16x8*>(&x_one[((size_t)b * L_ + lo) * D_ + d0 + dbase]) = v;
}

// 8 waves per block; wave w owns d = bx*8+w. Lane ln owns states n=ln, n=ln+64.
// bcts/dRs staged once, shared by all 8 waves. Per-8-step chunk: B/C rows
// preloaded as vector LDS reads; per-wave pt tile + float2 transpose-reduce.
__launch_bounds__(512)
__global__ void ssm_scan(const __bf16* __restrict__ dR,
                         const __bf16* __restrict__ bct,
                         const float* __restrict__ dt_w,
                         const float* __restrict__ dt_b,
                         const __bf16* __restrict__ xo_in,
                         const __bf16* __restrict__ xt_in,
                         const float* __restrict__ skip,
                         const float* __restrict__ A_log,
                         const float* __restrict__ Dp,
                         __bf16* __restrict__ out_mid)
{
    __shared__ u16 bcts[256 * 66];    // 33792 B
    __shared__ u16 dRs[64 * 66];      // 8448 B
    __shared__ float dtw_s[8][64];    // 2048 B
    __shared__ float2 dlx[8][64];     // 4096 B
    __shared__ float pt[8][8][66];    // 16896 B  (total 65280 B, 2 blocks/CU)
    const int tid = threadIdx.x;
    const int w = tid >> 6, ln = tid & 63;
    const int b = blockIdx.y;
    const int d = blockIdx.x * 8 + w;

    {   // stage bct[b]: 256 rows x 8 chunks (coalesced)
        const u16* src = (const u16*)bct + (size_t)b * 256 * 64;
        #pragma unroll
        for (int i = tid; i < 2048; i += 512) {
            int n = i >> 3, c = i & 7;
            *reinterpret_cast<u16x8*>(&bcts[n * 66 + c * 8]) =
                *reinterpret_cast<const u16x8*>(src + n * 64 + c * 8);
        }
        // stage dR[b]: 64 rows x 8 chunks
        const u16* srcd = (const u16*)dR + (size_t)b * 64 * 64;
        if (tid < 512) {
            int r = tid >> 3, c = tid & 7;
            *reinterpret_cast<u16x8*>(&dRs[r * 66 + c * 8]) =
                *reinterpret_cast<const u16x8*>(srcd + r * 64 + c * 8);
        }
    }
    dtw_s[w][ln] = dt_w[(size_t)d * 64 + ln];
    const float xo_own = (float)xo_in[((size_t)b * L_ + ln) * D_ + d];
    const float a0 = -__expf(A_log[(size_t)d * N_ + ln]);
    const float a1 = -__expf(A_log[(size_t)d * N_ + 64 + ln]);
    const float dtb = dt_b[d];
    __syncthreads();

    // delta(l=ln, d): 64-FMA dot, diagonal k-offset
    float accd = dtb;
    #pragma unroll
    for (int k = 0; k < 64; ++k) {
        int kk = (k + ln) & 63;
        accd = fmaf((float)*reinterpret_cast<const __bf16*>(&dRs[ln * 66 + kk]),
                    dtw_s[w][kk], accd);
    }
    const float dl_own = softplus_f(accd);
    dlx[w][ln] = make_float2(dl_own, xo_own);
    __syncthreads();

    float h0 = 0.f, h1 = 0.f, y_own = 0.f;
    const int rr = ln & 7, qs = ln >> 3;

    #pragma unroll
    for (int cc = 0; cc < 8; ++cc) {
        bf16x8 B0r = *reinterpret_cast<const bf16x8*>(&bcts[(      ln) * 66 + cc * 8]);
        bf16x8 B1r = *reinterpret_cast<const bf16x8*>(&bcts[( 64 + ln) * 66 + cc * 8]);
        bf16x8 C0r = *reinterpret_cast<const bf16x8*>(&bcts[(128 + ln) * 66 + cc * 8]);
        bf16x8 C1r = *reinterpret_cast<const bf16x8*>(&bcts[(192 + ln) * 66 + cc * 8]);
        #pragma unroll
        for (int r = 0; r < 8; ++r) {
            const int l = cc * 8 + r;
            float2 dd = dlx[w][l];
            float dx = dd.x * dd.y;
            h0 = fmaf(__expf(dd.x * a0), h0, dx * (float)B0r[r]);
            h1 = fmaf(__expf(dd.x * a1), h1, dx * (float)B1r[r]);
            pt[w][r][ln] = fmaf(h0, (float)C0r[r], h1 * (float)C1r[r]);
        }
        float sum = 0.f;
        #pragma unroll
        for (int j = 0; j < 4; ++j) {
            float2 v = *reinterpret_cast<const float2*>(&pt[w][rr][qs * 8 + j * 2]);
            sum += v.x + v.y;
        }
        sum += __shfl_xor(sum, 8, 64);
        sum += __shfl_xor(sum, 16, 64);
        sum += __shfl_xor(sum, 32, 64);
        if (qs == cc) y_own = sum;   // l = cc*8 + rr == ln
    }

    size_t idx = ((size_t)b * L_ + ln) * D_ + d;
    float y = y_own + Dp[d] * xo_own;
    out_mid[idx] = (__bf16)(y * (float)xt_in[idx] + skip[idx]);
}

extern "C" void kernel_launch(void* const* d_in, const int* in_sizes, int n_in,
                              void* d_out, int out_size, void* d_ws, size_t ws_size,
                              hipStream_t stream)
{
    const float* x      = (const float*)d_in[0];
    const float* proj_w = (const float*)d_in[1];
    const float* proj_b = (const float*)d_in[2];
    const float* conv_w = (const float*)d_in[3];
    const float* conv_b = (const float*)d_in[4];
    const float* dbc_w  = (const float*)d_in[5];
    const float* dt_w   = (const float*)d_in[6];
    const float* dt_b   = (const float*)d_in[7];
    const float* A_log  = (const float*)d_in[8];
    const float* Dp     = (const float*)d_in[9];
    float* out = (float*)d_out;

    __bf16* base    = (__bf16*)d_ws;
    __bf16* xp_b    = base;                   // 524288
    __bf16* xtwo_b  = xp_b + 524288;          // 524288
    __bf16* xone_b  = xtwo_b + 524288;        // 524288
    __bf16* dR_b    = xone_b + 524288;        // 32768   [b*64+l][64]
    __bf16* bct_b   = dR_b + 32768;           // 131072  [b][j][l]
    __bf16* omid_b  = bct_b + 131072;         // 524288
    __bf16* pw_b    = omid_b + 524288;        // 1048576
    __bf16* dbcw_b  = pw_b + 1048576;         // 327680
    __bf16* x_b     = dbcw_b + 327680;        // 524288

    // 0) f32 -> bf16 (weights + x)
    prep_bf16<<<928, 256, 0, stream>>>(proj_w, dbc_w, x, pw_b, dbcw_b, x_b);
    // 1) xp = x @ proj_w.T + b (bf16), x_two = silu(xp)
    gemm_mfma<32, 32, 2, 2, 1, 0, 0><<<dim3(32, 16), 256, 0, stream>>>(
        (const u16*)x_b, D_, (const u16*)pw_b, D_, proj_b, xp_b, xtwo_b, D_, D_);
    // 2) x_one = silu(conv(xp))
    conv_silu<<<dim3(32, B_), 256, 0, stream>>>(xp_b, conv_w, conv_b, xone_b);
    // 3) dbc = x_one @ dbc_w.T, split-written: dR row-major, bct transposed
    gemm_mfma<16, 32, 1, 2, 0, 0, 1><<<dim3(10, 32), 128, 0, stream>>>(
        (const u16*)xone_b, D_, (const u16*)dbcw_b, D_, nullptr, dR_b, bct_b, 320, D_);
    // 4+5) fused delta-GEMM + SSM scan + gating + skip
    ssm_scan<<<dim3(128, B_), 512, 0, stream>>>(
        dR_b, bct_b, dt_w, dt_b, xone_b, xtwo_b, x, A_log, Dp, omid_b);
    // 6) out = out_mid @ proj_w.T + proj_b  (f32 out)
    gemm_mfma<32, 32, 2, 2, 0, 1, 0><<<dim3(32, 16), 256, 0, stream>>>(
        (const u16*)omid_b, D_, (const u16*)pw_b, D_, proj_b, out, nullptr, D_, D_);
}